// Round 1
// baseline (168.904 us; speedup 1.0000x reference)
//
#include <hip/hip_runtime.h>

// Problem constants (fixed by reference)
#define BB 8
#define TT 16
#define DD 1024
#define NN 16
#define KHN 8      // K (kv heads)
#define HH 128
#define SS 8192
#define NPART 8    // S-partitions in attention kernel

typedef __attribute__((ext_vector_type(8))) short bf16x8;
typedef __attribute__((ext_vector_type(4))) float f32x4;

__device__ __forceinline__ unsigned short f2bf(float f) {
  unsigned u = __builtin_bit_cast(unsigned, f);
  u += 0x7FFFu + ((u >> 16) & 1u);
  return (unsigned short)(u >> 16);
}
__device__ __forceinline__ float bf2f(unsigned short h) {
  unsigned u = ((unsigned)h) << 16;
  return __builtin_bit_cast(float, u);
}
__device__ __forceinline__ f32x4 mfma16(bf16x8 a, bf16x8 b, f32x4 c) {
  return __builtin_amdgcn_mfma_f32_16x16x32_bf16(a, b, c, 0, 0, 0);
}
__device__ __forceinline__ void pack4(unsigned short* dst, float a, float b, float c, float d) {
  unsigned lo = (unsigned)f2bf(a) | ((unsigned)f2bf(b) << 16);
  unsigned hi = (unsigned)f2bf(c) | ((unsigned)f2bf(d) << 16);
  *(uint2*)dst = make_uint2(lo, hi);
}

// ---------------------------------------------------------------------------
// Kernel A: QKV projection GEMM.  C[128 x 4096] = x[128 x 1024] @ W[1024 x 4096]
// cols 0..2047 = Wq (ld 2048), 2048..3071 = Wk (ld 1024), 3072..4095 = Wv.
// Block tile 32x128, 4 waves (2x2), wave tile 16x64, K-step 32.
// ---------------------------------------------------------------------------
__global__ __launch_bounds__(256) void k_qkv_gemm(
    const float* __restrict__ x, const float* __restrict__ Wq,
    const float* __restrict__ Wk, const float* __restrict__ Wv,
    float* __restrict__ qkv) {
  __shared__ __align__(16) unsigned short Al[32][40];
  __shared__ __align__(16) unsigned short Bl[32][132];
  const int tid = threadIdx.x;
  const int lane = tid & 63, wv = tid >> 6;
  const int cc = lane & 15, g = lane >> 4;
  const int m0 = blockIdx.x * 32;
  const int cbk = blockIdx.y;
  const float* Wsrc;
  int ldw, n0;
  if (cbk < 16)      { Wsrc = Wq; ldw = 2048; n0 = cbk * 128; }
  else if (cbk < 24) { Wsrc = Wk; ldw = 1024; n0 = (cbk - 16) * 128; }
  else               { Wsrc = Wv; ldw = 1024; n0 = (cbk - 24) * 128; }
  const int rt = wv >> 1, cb0 = (wv & 1) * 64;
  f32x4 acc[4];
#pragma unroll
  for (int i = 0; i < 4; ++i) acc[i] = (f32x4)0.0f;

  for (int k0 = 0; k0 < 1024; k0 += 32) {
    { // stage A (x) 32x32 fp32 -> bf16
      int r = tid >> 3, c4 = (tid & 7) << 2;
      float4 f = *(const float4*)(x + (m0 + r) * 1024 + k0 + c4);
      pack4(&Al[r][c4], f.x, f.y, f.z, f.w);
    }
#pragma unroll
    for (int i = 0; i < 4; ++i) { // stage B (W) 32x128 fp32 -> bf16
      int ch = tid + (i << 8);
      int r = ch >> 5, c4 = (ch & 31) << 2;
      float4 f = *(const float4*)(Wsrc + (size_t)(k0 + r) * ldw + n0 + c4);
      pack4(&Bl[r][c4], f.x, f.y, f.z, f.w);
    }
    __syncthreads();
    bf16x8 af = *(const bf16x8*)&Al[rt * 16 + cc][g * 8];
#pragma unroll
    for (int ct = 0; ct < 4; ++ct) {
      bf16x8 bf;
#pragma unroll
      for (int j = 0; j < 8; ++j) bf[j] = (short)Bl[g * 8 + j][cb0 + ct * 16 + cc];
      acc[ct] = mfma16(af, bf, acc[ct]);
    }
    __syncthreads();
  }
#pragma unroll
  for (int ct = 0; ct < 4; ++ct)
#pragma unroll
    for (int r = 0; r < 4; ++r) {
      int row = m0 + rt * 16 + g * 4 + r;
      int col = cbk * 128 + cb0 + ct * 16 + cc;
      qkv[row * 4096 + col] = acc[ct][r];
    }
}

// ---------------------------------------------------------------------------
// Kernel B: RMSNorm (q,k) + RoPE (q,k) + bf16 conversion (q,k,v).
// grid (128 rows, 32 heads), block 128.  head id: 0..15 q, 16..23 k, 24..31 v.
// q gets attn scale H^-0.5 folded in.
// ---------------------------------------------------------------------------
__global__ __launch_bounds__(128) void k_normrope(
    const float* __restrict__ qkv, const float* __restrict__ qs,
    const float* __restrict__ ks, const int* __restrict__ seg,
    const int* __restrict__ cur_p,
    unsigned short* __restrict__ qa, unsigned short* __restrict__ ka,
    unsigned short* __restrict__ va) {
  __shared__ float lv[128];
  __shared__ float red[2];
  const int row = blockIdx.x, b = row >> 4, t = row & 15;
  const int hid = blockIdx.y;
  const int h = threadIdx.x;
  float val;
  if (hid < 16)      val = qkv[row * 4096 + hid * 128 + h];
  else if (hid < 24) val = qkv[row * 4096 + 2048 + (hid - 16) * 128 + h];
  else               val = qkv[row * 4096 + 3072 + (hid - 24) * 128 + h];

  if (hid >= 24) { // v path: plain bf16 store
    int kh = hid - 24;
    va[((b * KHN + kh) * TT + t) * 128 + h] = f2bf(val);
    return;
  }
  // rmsnorm over 128
  float ss = val * val;
#pragma unroll
  for (int m = 1; m < 64; m <<= 1) ss += __shfl_xor(ss, m, 64);
  int wid = threadIdx.x >> 6, lane = threadIdx.x & 63;
  if (lane == 0) red[wid] = ss;
  __syncthreads();
  float mean = (red[0] + red[1]) * (1.0f / 128.0f);
  float scl = (hid < 16) ? qs[h] : ks[h];
  float nrm = val * (1.0f / sqrtf(mean + 1e-6f)) * scl;
  lv[h] = nrm;
  __syncthreads();
  float prt = lv[h ^ 64];
  // position
  const int cur = cur_p[0];
  int first = TT;
#pragma unroll
  for (int i = TT - 1; i >= 0; --i)
    if (seg[b * TT + i] != 0) first = i;
  float posf;
  if (seg[b * TT + t] != 0) posf = (float)(t - first + cur);
  else                      posf = (float)(1073741824 + cur);
  int j = h & 63;
  float inv = powf(1.0e6f, -((float)j) * (1.0f / 64.0f));
  float ang = posf * inv;
  float sn = sinf(ang), cs = cosf(ang);
  float outv = (h < 64) ? (nrm * cs - prt * sn) : (nrm * cs + prt * sn);
  if (hid < 16) {
    int kh = hid >> 1, gq = hid & 1;
    qa[((b * KHN + kh) * 32 + gq * 16 + t) * 128 + h] =
        f2bf(outv * 0.08838834764831845f); // * H^-0.5
  } else {
    int kh = hid - 16;
    ka[((b * KHN + kh) * TT + t) * 128 + h] = f2bf(outv);
  }
}

// ---------------------------------------------------------------------------
// Kernel C: flash attention partials.
// grid (64 pairs, NPART),  block 256 = 4 waves.
// Each wave: Q tile 32 rows (g*16+t) x 128, iterates 32-position KV tiles
// (tiles strided by 4 within this block's S-partition).
// K: staged to per-wave LDS (coalesced float4 -> bf16), V: direct per-lane.
// Ends with 4-wave merge -> one partial (m,l,O) per block.
// ---------------------------------------------------------------------------
__global__ __launch_bounds__(256, 2) void k_attn(
    const float* __restrict__ kcache, const float* __restrict__ vcache,
    const unsigned short* __restrict__ qa, const unsigned short* __restrict__ ka,
    const unsigned short* __restrict__ va, const int* __restrict__ seg,
    const int* __restrict__ sind, const int* __restrict__ cur_p,
    float* __restrict__ partO, float* __restrict__ partML) {
  __shared__ __align__(16) unsigned short Kl[4][32][132]; // 33792 B (merge scratch overlays)
  __shared__ __align__(16) unsigned short Pl[4][32][40];  // 10240 B
  __shared__ float mls[2][32][2];
  const int tid = threadIdx.x, wv = tid >> 6, lane = tid & 63;
  const int cc = lane & 15, g = lane >> 4;
  const int pair = blockIdx.x, b = pair >> 3, kh = pair & 7;
  const int qi = blockIdx.y;
  const int cur = cur_p[0];
  const int len = cur + TT;
  int start_b = sind[b];
  if (start_b < 0) {
    int first = TT;
#pragma unroll
    for (int i = TT - 1; i >= 0; --i)
      if (seg[b * TT + i] != 0) first = i;
    start_b = first;
  }
  const int NTt = (len + 31) >> 5;
  const int L = (NTt + NPART - 1) / NPART;
  const int tlo = qi * L;
  const int thi = (tlo + L < NTt) ? (tlo + L) : NTt;

  // persistent Q fragments
  bf16x8 qf[2][4];
  {
    const unsigned short* qb = qa + ((size_t)pair * 32) * 128;
#pragma unroll
    for (int rb = 0; rb < 2; ++rb)
#pragma unroll
      for (int kk = 0; kk < 4; ++kk)
        qf[rb][kk] = *(const bf16x8*)(qb + (rb * 16 + cc) * 128 + kk * 32 + g * 8);
  }
  const float* kcb = kcache + (size_t)b * (SS * 1024) + kh * 128;
  const float* vcb = vcache + (size_t)b * (SS * 1024) + kh * 128;
  const unsigned short* knb = ka + (size_t)(b * KHN + kh) * (TT * 128);
  const unsigned short* vnb = va + (size_t)(b * KHN + kh) * (TT * 128);

  f32x4 acc[2][8];
  float mreg[2][4], lreg[2][4];
#pragma unroll
  for (int rb = 0; rb < 2; ++rb) {
#pragma unroll
    for (int hb = 0; hb < 8; ++hb) acc[rb][hb] = (f32x4)0.0f;
#pragma unroll
    for (int r = 0; r < 4; ++r) { mreg[rb][r] = -1e30f; lreg[rb][r] = 0.0f; }
  }

  for (int tile = tlo + wv; tile < thi; tile += 4) {
    const int ts0 = tile << 5;
    // ---- stage K tile (32 x 128) into Kl[wv]
    if (ts0 + 32 <= cur) {
#pragma unroll
      for (int i = 0; i < 16; ++i) {
        int ch = lane + (i << 6);
        int r = ch >> 5, c4 = (ch & 31) << 2;
        float4 f = *(const float4*)(kcb + (size_t)(ts0 + r) * 1024 + c4);
        pack4(&Kl[wv][r][c4], f.x, f.y, f.z, f.w);
      }
    } else {
#pragma unroll
      for (int i = 0; i < 16; ++i) {
        int ch = lane + (i << 6);
        int r = ch >> 5, c4 = (ch & 31) << 2;
        int ts = ts0 + r;
        if (ts < cur) {
          float4 f = *(const float4*)(kcb + (size_t)ts * 1024 + c4);
          pack4(&Kl[wv][r][c4], f.x, f.y, f.z, f.w);
        } else {
          int tr = ts - cur; if (tr > TT - 1) tr = TT - 1;
          ushort4 u = *(const ushort4*)(knb + tr * 128 + c4);
          *(ushort4*)&Kl[wv][r][c4] = u;
        }
      }
    }
    __builtin_amdgcn_wave_barrier();
    // ---- V fragments (direct global, B-layout: k=g*8+j rows, col=h)
    bf16x8 vf[8];
    if (ts0 + 32 <= cur) {
#pragma unroll
      for (int hb = 0; hb < 8; ++hb) {
        int hc = hb * 16 + cc;
#pragma unroll
        for (int j = 0; j < 8; ++j) {
          int ts = ts0 + g * 8 + j;
          vf[hb][j] = (short)f2bf(vcb[(size_t)ts * 1024 + hc]);
        }
      }
    } else {
#pragma unroll
      for (int hb = 0; hb < 8; ++hb) {
        int hc = hb * 16 + cc;
#pragma unroll
        for (int j = 0; j < 8; ++j) {
          int ts = ts0 + g * 8 + j;
          float vvf;
          if (ts < cur) vvf = vcb[(size_t)ts * 1024 + hc];
          else { int tr = ts - cur; if (tr > TT - 1) tr = TT - 1; vvf = bf2f(vnb[tr * 128 + hc]); }
          vf[hb][j] = (short)f2bf(vvf);
        }
      }
    }
    // ---- QK^T : s[rb][cb], C layout col=kv(cc), row=q(g*4+r)
    f32x4 s[2][2];
#pragma unroll
    for (int rb = 0; rb < 2; ++rb)
#pragma unroll
      for (int cb = 0; cb < 2; ++cb) s[rb][cb] = (f32x4)0.0f;
#pragma unroll
    for (int kk = 0; kk < 4; ++kk) {
#pragma unroll
      for (int cb = 0; cb < 2; ++cb) {
        const unsigned short* kp = &Kl[wv][cb * 16 + cc][kk * 32 + g * 8];
        uint2 lo = *(const uint2*)kp;
        uint2 hi = *(const uint2*)(kp + 4);
        bf16x8 kf = __builtin_bit_cast(bf16x8, make_uint4(lo.x, lo.y, hi.x, hi.y));
        s[0][cb] = mfma16(qf[0][kk], kf, s[0][cb]);
        s[1][cb] = mfma16(qf[1][kk], kf, s[1][cb]);
      }
    }
    // ---- mask + online softmax
    float al[2][4];
#pragma unroll
    for (int rb = 0; rb < 2; ++rb) {
#pragma unroll
      for (int r = 0; r < 4; ++r) {
        const int tq = g * 4 + r; // query token index (same for both rb)
#pragma unroll
        for (int cb = 0; cb < 2; ++cb) {
          int ts = ts0 + cb * 16 + cc;
          bool ok = (ts >= start_b) && (ts <= cur + tq);
          if (!ok) s[rb][cb][r] = -1e30f;
        }
        float tm = fmaxf(s[rb][0][r], s[rb][1][r]);
#pragma unroll
        for (int m = 1; m < 16; m <<= 1) tm = fmaxf(tm, __shfl_xor(tm, m, 64));
        float mn = fmaxf(mreg[rb][r], tm);
        float a = __expf(mreg[rb][r] - mn);
        float p0 = (s[rb][0][r] < -1e29f) ? 0.0f : __expf(s[rb][0][r] - mn);
        float p1 = (s[rb][1][r] < -1e29f) ? 0.0f : __expf(s[rb][1][r] - mn);
        s[rb][0][r] = p0; s[rb][1][r] = p1;
        float rs = p0 + p1;
#pragma unroll
        for (int m = 1; m < 16; m <<= 1) rs += __shfl_xor(rs, m, 64);
        lreg[rb][r] = lreg[rb][r] * a + rs;
        mreg[rb][r] = mn;
        al[rb][r] = a;
      }
    }
    // ---- P -> LDS (C layout) -> A-frag layout
#pragma unroll
    for (int rb = 0; rb < 2; ++rb)
#pragma unroll
      for (int cb = 0; cb < 2; ++cb)
#pragma unroll
        for (int r = 0; r < 4; ++r)
          Pl[wv][rb * 16 + g * 4 + r][cb * 16 + cc] = f2bf(s[rb][cb][r]);
    __builtin_amdgcn_wave_barrier();
    bf16x8 pf[2];
#pragma unroll
    for (int rb = 0; rb < 2; ++rb)
      pf[rb] = *(const bf16x8*)&Pl[wv][rb * 16 + cc][g * 8];
    // ---- rescale + PV
#pragma unroll
    for (int rb = 0; rb < 2; ++rb)
#pragma unroll
      for (int hb = 0; hb < 8; ++hb) {
        f32x4 t = acc[rb][hb];
#pragma unroll
        for (int r = 0; r < 4; ++r) t[r] *= al[rb][r];
        acc[rb][hb] = mfma16(pf[rb], vf[hb], t);
      }
  }

  // ---- merge 4 wave-partials -> 1 block partial (scratch overlays Kl)
  float* Oscr = (float*)&Kl[0][0][0]; // 2 x 32 x 128 floats = 32 KB <= 33 KB
  auto dump = [&](int sid) {
#pragma unroll
    for (int rb = 0; rb < 2; ++rb)
#pragma unroll
      for (int hb = 0; hb < 8; ++hb)
#pragma unroll
        for (int r = 0; r < 4; ++r)
          Oscr[(sid * 32 + rb * 16 + g * 4 + r) * 128 + hb * 16 + cc] = acc[rb][hb][r];
    if (cc == 0) {
#pragma unroll
      for (int rb = 0; rb < 2; ++rb)
#pragma unroll
        for (int r = 0; r < 4; ++r) {
          mls[sid][rb * 16 + g * 4 + r][0] = mreg[rb][r];
          mls[sid][rb * 16 + g * 4 + r][1] = lreg[rb][r];
        }
    }
  };
  auto mergefrom = [&](int sid) {
    float a0s[2][4], a1s[2][4];
#pragma unroll
    for (int rb = 0; rb < 2; ++rb)
#pragma unroll
      for (int r = 0; r < 4; ++r) {
        int row = rb * 16 + g * 4 + r;
        float mp = mls[sid][row][0], lp = mls[sid][row][1];
        float M = fmaxf(mreg[rb][r], mp);
        float a0 = __expf(mreg[rb][r] - M), a1 = __expf(mp - M);
        lreg[rb][r] = lreg[rb][r] * a0 + lp * a1;
        mreg[rb][r] = M;
        a0s[rb][r] = a0; a1s[rb][r] = a1;
      }
#pragma unroll
    for (int rb = 0; rb < 2; ++rb)
#pragma unroll
      for (int hb = 0; hb < 8; ++hb)
#pragma unroll
        for (int r = 0; r < 4; ++r) {
          int row = rb * 16 + g * 4 + r;
          acc[rb][hb][r] = acc[rb][hb][r] * a0s[rb][r] +
                           Oscr[(sid * 32 + row) * 128 + hb * 16 + cc] * a1s[rb][r];
        }
  };
  __syncthreads();
  if (wv >= 2) dump(wv - 2);
  __syncthreads();
  if (wv < 2) mergefrom(wv);
  __syncthreads();
  if (wv == 1) dump(0);
  __syncthreads();
  if (wv == 0) {
    mergefrom(0);
    size_t pidx = (size_t)pair * NPART + qi;
#pragma unroll
    for (int rb = 0; rb < 2; ++rb)
#pragma unroll
      for (int hb = 0; hb < 8; ++hb)
#pragma unroll
        for (int r = 0; r < 4; ++r)
          partO[(pidx * 32 + rb * 16 + g * 4 + r) * 128 + hb * 16 + cc] = acc[rb][hb][r];
    if (cc == 0) {
#pragma unroll
      for (int rb = 0; rb < 2; ++rb)
#pragma unroll
        for (int r = 0; r < 4; ++r) {
          partML[pidx * 64 + (rb * 16 + g * 4 + r) * 2 + 0] = mreg[rb][r];
          partML[pidx * 64 + (rb * 16 + g * 4 + r) * 2 + 1] = lreg[rb][r];
        }
    }
  }
}

// ---------------------------------------------------------------------------
// Kernel D1: combine NPART partials per (b,kh), normalize, write o as bf16
// in [b][t][n][h] layout for the output GEMM.
// ---------------------------------------------------------------------------
__global__ __launch_bounds__(256) void k_combine(
    const float* __restrict__ partO, const float* __restrict__ partML,
    unsigned short* __restrict__ obf) {
  __shared__ float sc[NPART][32];
  const int pair = blockIdx.x, b = pair >> 3, kh = pair & 7;
  const int tid = threadIdx.x;
  if (tid < 32) {
    float mm[NPART], ll[NPART];
    float M = -3.0e38f;
#pragma unroll
    for (int p = 0; p < NPART; ++p) {
      mm[p] = partML[((size_t)pair * NPART + p) * 64 + tid * 2 + 0];
      ll[p] = partML[((size_t)pair * NPART + p) * 64 + tid * 2 + 1];
      M = fmaxf(M, mm[p]);
    }
    float denom = 0.0f;
#pragma unroll
    for (int p = 0; p < NPART; ++p) denom += __expf(mm[p] - M) * ll[p];
    float inv = (denom > 0.0f) ? 1.0f / denom : 0.0f;
#pragma unroll
    for (int p = 0; p < NPART; ++p) sc[p][tid] = __expf(mm[p] - M) * inv;
  }
  __syncthreads();
#pragma unroll
  for (int i = 0; i < 16; ++i) {
    int idx = tid + (i << 8);
    int row = idx >> 7, hc = idx & 127;
    float o = 0.0f;
#pragma unroll
    for (int p = 0; p < NPART; ++p)
      o += partO[(((size_t)pair * NPART + p) * 32 + row) * 128 + hc] * sc[p][row];
    int gq = row >> 4, t = row & 15, n = kh * 2 + gq;
    obf[((b * TT + t) * NN + n) * 128 + hc] = f2bf(o);
  }
}

// ---------------------------------------------------------------------------
// Kernel D2: output projection.  out[128 x 1024] = o[128 x 2048] @ Wo[2048 x 1024]
// ---------------------------------------------------------------------------
__global__ __launch_bounds__(256) void k_out_gemm(
    const unsigned short* __restrict__ obf, const float* __restrict__ Wo,
    float* __restrict__ out) {
  __shared__ __align__(16) unsigned short Al[32][40];
  __shared__ __align__(16) unsigned short Bl[32][68];
  const int tid = threadIdx.x, lane = tid & 63, wv = tid >> 6;
  const int cc = lane & 15, g = lane >> 4;
  const int m0 = blockIdx.x * 32, n0 = blockIdx.y * 64;
  const int rt = wv >> 1, cb0 = (wv & 1) * 32;
  f32x4 acc[2];
#pragma unroll
  for (int i = 0; i < 2; ++i) acc[i] = (f32x4)0.0f;

  for (int k0 = 0; k0 < 2048; k0 += 32) {
    { // stage A (bf16 already)
      int r = tid >> 3, c4 = (tid & 7) << 2;
      ushort4 u = *(const ushort4*)(obf + (m0 + r) * 2048 + k0 + c4);
      *(ushort4*)&Al[r][c4] = u;
    }
#pragma unroll
    for (int i = 0; i < 2; ++i) { // stage B (Wo fp32 -> bf16)
      int ch = tid + (i << 8);
      int r = ch >> 4, c4 = (ch & 15) << 2;
      float4 f = *(const float4*)(Wo + (size_t)(k0 + r) * 1024 + n0 + c4);
      pack4(&Bl[r][c4], f.x, f.y, f.z, f.w);
    }
    __syncthreads();
    bf16x8 af = *(const bf16x8*)&Al[rt * 16 + cc][g * 8];
#pragma unroll
    for (int ct = 0; ct < 2; ++ct) {
      bf16x8 bf;
#pragma unroll
      for (int j = 0; j < 8; ++j) bf[j] = (short)Bl[g * 8 + j][cb0 + ct * 16 + cc];
      acc[ct] = mfma16(af, bf, acc[ct]);
    }
    __syncthreads();
  }
#pragma unroll
  for (int ct = 0; ct < 2; ++ct)
#pragma unroll
    for (int r = 0; r < 4; ++r)
      out[(m0 + rt * 16 + g * 4 + r) * 1024 + n0 + cb0 + ct * 16 + cc] = acc[ct][r];
}

// ---------------------------------------------------------------------------
extern "C" void kernel_launch(void* const* d_in, const int* in_sizes, int n_in,
                              void* d_out, int out_size, void* d_ws, size_t ws_size,
                              hipStream_t stream) {
  (void)in_sizes; (void)n_in; (void)out_size; (void)ws_size;
  const float* x   = (const float*)d_in[0];
  const float* Wq  = (const float*)d_in[1];
  const float* Wk  = (const float*)d_in[2];
  const float* Wv  = (const float*)d_in[3];
  const float* Wo  = (const float*)d_in[4];
  const float* qs  = (const float*)d_in[5];
  const float* ks  = (const float*)d_in[6];
  const float* kc  = (const float*)d_in[7];
  const float* vc  = (const float*)d_in[8];
  const int* seg   = (const int*)d_in[9];
  const int* sind  = (const int*)d_in[10];
  const int* curp  = (const int*)d_in[11];
  float* out = (float*)d_out;

  char* ws = (char*)d_ws;
  float*          qkv    = (float*)(ws + 0);                 // 2,097,152 B
  unsigned short* qa     = (unsigned short*)(ws + 2097152);  //   524,288 B
  unsigned short* ka     = (unsigned short*)(ws + 2621440);  //   262,144 B
  unsigned short* va     = (unsigned short*)(ws + 2883584);  //   262,144 B
  float*          partO  = (float*)(ws + 3145728);           // 8,388,608 B
  float*          partML = (float*)(ws + 11534336);          //   131,072 B
  unsigned short* obf    = (unsigned short*)(ws + 11665408); //   524,288 B

  k_qkv_gemm<<<dim3(4, 32), 256, 0, stream>>>(x, Wq, Wk, Wv, qkv);
  k_normrope<<<dim3(128, 32), 128, 0, stream>>>(qkv, qs, ks, seg, curp, qa, ka, va);
  k_attn<<<dim3(64, NPART), 256, 0, stream>>>(kc, vc, qa, ka, va, seg, sind, curp, partO, partML);
  k_combine<<<64, 256, 0, stream>>>(partO, partML, obf);
  k_out_gemm<<<dim3(4, 16), 256, 0, stream>>>(obf, Wo, out);
}

// Round 2
// 139.411 us; speedup vs baseline: 1.2116x; 1.2116x over previous
//
#include <hip/hip_runtime.h>

// Problem constants (fixed by reference)
#define BB 8
#define TT 16
#define DD 1024
#define NN 16
#define KHN 8      // K (kv heads)
#define HH 128
#define SS 8192
#define NPART 8    // S-partitions in attention kernel

typedef __attribute__((ext_vector_type(8))) short bf16x8;
typedef __attribute__((ext_vector_type(4))) float f32x4;

__device__ __forceinline__ unsigned short f2bf(float f) {
  unsigned u = __builtin_bit_cast(unsigned, f);
  u += 0x7FFFu + ((u >> 16) & 1u);
  return (unsigned short)(u >> 16);
}
__device__ __forceinline__ float bf2f(unsigned short h) {
  unsigned u = ((unsigned)h) << 16;
  return __builtin_bit_cast(float, u);
}
__device__ __forceinline__ f32x4 mfma16(bf16x8 a, bf16x8 b, f32x4 c) {
  return __builtin_amdgcn_mfma_f32_16x16x32_bf16(a, b, c, 0, 0, 0);
}
__device__ __forceinline__ void pack4(unsigned short* dst, float a, float b, float c, float d) {
  unsigned lo = (unsigned)f2bf(a) | ((unsigned)f2bf(b) << 16);
  unsigned hi = (unsigned)f2bf(c) | ((unsigned)f2bf(d) << 16);
  *(uint2*)dst = make_uint2(lo, hi);
}

// ---------------------------------------------------------------------------
// Kernel P: transpose + bf16-cast all weights once.
//   Wt1[4096][1024] <- [Wq | Wk | Wv] columns    (rows n, k-contiguous)
//   Wt2[1024][2048] <- Wo^T                      (rows d, n-contiguous)
// grid (32, 32, 4) with guards; 64x64 tiles via LDS.
// ---------------------------------------------------------------------------
__global__ __launch_bounds__(256) void k_wtrans(
    const float* __restrict__ Wq, const float* __restrict__ Wk,
    const float* __restrict__ Wv, const float* __restrict__ Wo,
    unsigned short* __restrict__ Wt1, unsigned short* __restrict__ Wt2) {
  __shared__ __align__(16) unsigned short Tl[64][66];
  const int tid = threadIdx.x;
  const int z = blockIdx.z;
  const float* src; int K, N; unsigned short* dst;
  if (z == 0)      { src = Wq; K = 1024; N = 2048; dst = Wt1; }
  else if (z == 1) { src = Wk; K = 1024; N = 1024; dst = Wt1 + (size_t)2048 * 1024; }
  else if (z == 2) { src = Wv; K = 1024; N = 1024; dst = Wt1 + (size_t)3072 * 1024; }
  else             { src = Wo; K = 2048; N = 1024; dst = Wt2; }
  const int n0 = blockIdx.x * 64, k0 = blockIdx.y * 64;
  if (n0 >= N || k0 >= K) return;
  { // load 64(k) x 64(n) fp32, cast, store row-major [k][n] in LDS
    const int r = tid >> 4, c4 = (tid & 15) << 2;
#pragma unroll
    for (int p = 0; p < 4; ++p) {
      const int k = p * 16 + r;
      float4 f = *(const float4*)(src + (size_t)(k0 + k) * N + n0 + c4);
      pack4(&Tl[k][c4], f.x, f.y, f.z, f.w);
    }
  }
  __syncthreads();
  { // write transposed: dst[n][k], lanes cover k-chunks for coalescing
    const int c8 = tid & 7, nb = tid >> 3; // c8: k-chunk, nb: 0..31
#pragma unroll
    for (int p = 0; p < 2; ++p) {
      const int n = p * 32 + nb;
      unsigned short tmp[8];
#pragma unroll
      for (int j = 0; j < 8; ++j) tmp[j] = Tl[c8 * 8 + j][n];
      unsigned short* dp = dst + (size_t)(n0 + n) * K + k0 + c8 * 8;
      *(uint4*)dp = *(const uint4*)&tmp[0];
    }
  }
}

// ---------------------------------------------------------------------------
// Kernel A: QKV projection GEMM, LDS-free / barrier-free.
// C[128 x 4096] = x[128 x 1024] @ Wt1^T  (Wt1 is [n][k] bf16)
// grid (4 m-tiles, 32 n-panels), block 256 = 4 waves (2m x 2n), wave 16x64.
// ---------------------------------------------------------------------------
__global__ __launch_bounds__(256) void k_qkv_gemm(
    const float* __restrict__ x, const unsigned short* __restrict__ Wt1,
    float* __restrict__ qkv) {
  const int tid = threadIdx.x, lane = tid & 63, wv = tid >> 6;
  const int cc = lane & 15, g = lane >> 4;
  const int m0 = blockIdx.x * 32, n0 = blockIdx.y * 128;
  const int rt = wv >> 1, cb0 = (wv & 1) * 64;
  const int m = m0 + rt * 16 + cc;
  f32x4 acc[4];
#pragma unroll
  for (int i = 0; i < 4; ++i) acc[i] = (f32x4)0.0f;

#pragma unroll 4
  for (int k0 = 0; k0 < 1024; k0 += 32) {
    float4 fa = *(const float4*)(x + (size_t)m * 1024 + k0 + g * 8);
    float4 fb = *(const float4*)(x + (size_t)m * 1024 + k0 + g * 8 + 4);
    bf16x8 af;
    af[0] = (short)f2bf(fa.x); af[1] = (short)f2bf(fa.y);
    af[2] = (short)f2bf(fa.z); af[3] = (short)f2bf(fa.w);
    af[4] = (short)f2bf(fb.x); af[5] = (short)f2bf(fb.y);
    af[6] = (short)f2bf(fb.z); af[7] = (short)f2bf(fb.w);
#pragma unroll
    for (int ct = 0; ct < 4; ++ct) {
      const int n = n0 + cb0 + ct * 16 + cc;
      bf16x8 bf = *(const bf16x8*)(Wt1 + (size_t)n * 1024 + k0 + g * 8);
      acc[ct] = mfma16(af, bf, acc[ct]);
    }
  }
#pragma unroll
  for (int ct = 0; ct < 4; ++ct)
#pragma unroll
    for (int r = 0; r < 4; ++r) {
      int row = m0 + rt * 16 + g * 4 + r;
      int col = n0 + cb0 + ct * 16 + cc;
      qkv[(size_t)row * 4096 + col] = acc[ct][r];
    }
}

// ---------------------------------------------------------------------------
// Kernel B: RMSNorm (q,k) + RoPE (q,k) + bf16 conversion (q,k,v). (unchanged)
// ---------------------------------------------------------------------------
__global__ __launch_bounds__(128) void k_normrope(
    const float* __restrict__ qkv, const float* __restrict__ qs,
    const float* __restrict__ ks, const int* __restrict__ seg,
    const int* __restrict__ cur_p,
    unsigned short* __restrict__ qa, unsigned short* __restrict__ ka,
    unsigned short* __restrict__ va) {
  __shared__ float lv[128];
  __shared__ float red[2];
  const int row = blockIdx.x, b = row >> 4, t = row & 15;
  const int hid = blockIdx.y;
  const int h = threadIdx.x;
  float val;
  if (hid < 16)      val = qkv[row * 4096 + hid * 128 + h];
  else if (hid < 24) val = qkv[row * 4096 + 2048 + (hid - 16) * 128 + h];
  else               val = qkv[row * 4096 + 3072 + (hid - 24) * 128 + h];

  if (hid >= 24) { // v path: plain bf16 store
    int kh = hid - 24;
    va[((b * KHN + kh) * TT + t) * 128 + h] = f2bf(val);
    return;
  }
  // rmsnorm over 128
  float ss = val * val;
#pragma unroll
  for (int m = 1; m < 64; m <<= 1) ss += __shfl_xor(ss, m, 64);
  int wid = threadIdx.x >> 6, lane = threadIdx.x & 63;
  if (lane == 0) red[wid] = ss;
  __syncthreads();
  float mean = (red[0] + red[1]) * (1.0f / 128.0f);
  float scl = (hid < 16) ? qs[h] : ks[h];
  float nrm = val * (1.0f / sqrtf(mean + 1e-6f)) * scl;
  lv[h] = nrm;
  __syncthreads();
  float prt = lv[h ^ 64];
  // position
  const int cur = cur_p[0];
  int first = TT;
#pragma unroll
  for (int i = TT - 1; i >= 0; --i)
    if (seg[b * TT + i] != 0) first = i;
  float posf;
  if (seg[b * TT + t] != 0) posf = (float)(t - first + cur);
  else                      posf = (float)(1073741824 + cur);
  int j = h & 63;
  float inv = powf(1.0e6f, -((float)j) * (1.0f / 64.0f));
  float ang = posf * inv;
  float sn = sinf(ang), cs = cosf(ang);
  float outv = (h < 64) ? (nrm * cs - prt * sn) : (nrm * cs + prt * sn);
  if (hid < 16) {
    int kh = hid >> 1, gq = hid & 1;
    qa[((b * KHN + kh) * 32 + gq * 16 + t) * 128 + h] =
        f2bf(outv * 0.08838834764831845f); // * H^-0.5
  } else {
    int kh = hid - 16;
    ka[((b * KHN + kh) * TT + t) * 128 + h] = f2bf(outv);
  }
}

// ---------------------------------------------------------------------------
// Kernel C: flash attention partials. (unchanged)
// ---------------------------------------------------------------------------
__global__ __launch_bounds__(256, 2) void k_attn(
    const float* __restrict__ kcache, const float* __restrict__ vcache,
    const unsigned short* __restrict__ qa, const unsigned short* __restrict__ ka,
    const unsigned short* __restrict__ va, const int* __restrict__ seg,
    const int* __restrict__ sind, const int* __restrict__ cur_p,
    float* __restrict__ partO, float* __restrict__ partML) {
  __shared__ __align__(16) unsigned short Kl[4][32][132]; // 33792 B (merge scratch overlays)
  __shared__ __align__(16) unsigned short Pl[4][32][40];  // 10240 B
  __shared__ float mls[2][32][2];
  const int tid = threadIdx.x, wv = tid >> 6, lane = tid & 63;
  const int cc = lane & 15, g = lane >> 4;
  const int pair = blockIdx.x, b = pair >> 3, kh = pair & 7;
  const int qi = blockIdx.y;
  const int cur = cur_p[0];
  const int len = cur + TT;
  int start_b = sind[b];
  if (start_b < 0) {
    int first = TT;
#pragma unroll
    for (int i = TT - 1; i >= 0; --i)
      if (seg[b * TT + i] != 0) first = i;
    start_b = first;
  }
  const int NTt = (len + 31) >> 5;
  const int L = (NTt + NPART - 1) / NPART;
  const int tlo = qi * L;
  const int thi = (tlo + L < NTt) ? (tlo + L) : NTt;

  // persistent Q fragments
  bf16x8 qf[2][4];
  {
    const unsigned short* qb = qa + ((size_t)pair * 32) * 128;
#pragma unroll
    for (int rb = 0; rb < 2; ++rb)
#pragma unroll
      for (int kk = 0; kk < 4; ++kk)
        qf[rb][kk] = *(const bf16x8*)(qb + (rb * 16 + cc) * 128 + kk * 32 + g * 8);
  }
  const float* kcb = kcache + (size_t)b * (SS * 1024) + kh * 128;
  const float* vcb = vcache + (size_t)b * (SS * 1024) + kh * 128;
  const unsigned short* knb = ka + (size_t)(b * KHN + kh) * (TT * 128);
  const unsigned short* vnb = va + (size_t)(b * KHN + kh) * (TT * 128);

  f32x4 acc[2][8];
  float mreg[2][4], lreg[2][4];
#pragma unroll
  for (int rb = 0; rb < 2; ++rb) {
#pragma unroll
    for (int hb = 0; hb < 8; ++hb) acc[rb][hb] = (f32x4)0.0f;
#pragma unroll
    for (int r = 0; r < 4; ++r) { mreg[rb][r] = -1e30f; lreg[rb][r] = 0.0f; }
  }

  for (int tile = tlo + wv; tile < thi; tile += 4) {
    const int ts0 = tile << 5;
    // ---- stage K tile (32 x 128) into Kl[wv]
    if (ts0 + 32 <= cur) {
#pragma unroll
      for (int i = 0; i < 16; ++i) {
        int ch = lane + (i << 6);
        int r = ch >> 5, c4 = (ch & 31) << 2;
        float4 f = *(const float4*)(kcb + (size_t)(ts0 + r) * 1024 + c4);
        pack4(&Kl[wv][r][c4], f.x, f.y, f.z, f.w);
      }
    } else {
#pragma unroll
      for (int i = 0; i < 16; ++i) {
        int ch = lane + (i << 6);
        int r = ch >> 5, c4 = (ch & 31) << 2;
        int ts = ts0 + r;
        if (ts < cur) {
          float4 f = *(const float4*)(kcb + (size_t)ts * 1024 + c4);
          pack4(&Kl[wv][r][c4], f.x, f.y, f.z, f.w);
        } else {
          int tr = ts - cur; if (tr > TT - 1) tr = TT - 1;
          ushort4 u = *(const ushort4*)(knb + tr * 128 + c4);
          *(ushort4*)&Kl[wv][r][c4] = u;
        }
      }
    }
    __builtin_amdgcn_wave_barrier();
    // ---- V fragments (direct global, B-layout: k=g*8+j rows, col=h)
    bf16x8 vf[8];
    if (ts0 + 32 <= cur) {
#pragma unroll
      for (int hb = 0; hb < 8; ++hb) {
        int hc = hb * 16 + cc;
#pragma unroll
        for (int j = 0; j < 8; ++j) {
          int ts = ts0 + g * 8 + j;
          vf[hb][j] = (short)f2bf(vcb[(size_t)ts * 1024 + hc]);
        }
      }
    } else {
#pragma unroll
      for (int hb = 0; hb < 8; ++hb) {
        int hc = hb * 16 + cc;
#pragma unroll
        for (int j = 0; j < 8; ++j) {
          int ts = ts0 + g * 8 + j;
          float vvf;
          if (ts < cur) vvf = vcb[(size_t)ts * 1024 + hc];
          else { int tr = ts - cur; if (tr > TT - 1) tr = TT - 1; vvf = bf2f(vnb[tr * 128 + hc]); }
          vf[hb][j] = (short)f2bf(vvf);
        }
      }
    }
    // ---- QK^T : s[rb][cb], C layout col=kv(cc), row=q(g*4+r)
    f32x4 s[2][2];
#pragma unroll
    for (int rb = 0; rb < 2; ++rb)
#pragma unroll
      for (int cb = 0; cb < 2; ++cb) s[rb][cb] = (f32x4)0.0f;
#pragma unroll
    for (int kk = 0; kk < 4; ++kk) {
#pragma unroll
      for (int cb = 0; cb < 2; ++cb) {
        const unsigned short* kp = &Kl[wv][cb * 16 + cc][kk * 32 + g * 8];
        uint2 lo = *(const uint2*)kp;
        uint2 hi = *(const uint2*)(kp + 4);
        bf16x8 kf = __builtin_bit_cast(bf16x8, make_uint4(lo.x, lo.y, hi.x, hi.y));
        s[0][cb] = mfma16(qf[0][kk], kf, s[0][cb]);
        s[1][cb] = mfma16(qf[1][kk], kf, s[1][cb]);
      }
    }
    // ---- mask + online softmax
    float al[2][4];
#pragma unroll
    for (int rb = 0; rb < 2; ++rb) {
#pragma unroll
      for (int r = 0; r < 4; ++r) {
        const int tq = g * 4 + r; // query token index (same for both rb)
#pragma unroll
        for (int cb = 0; cb < 2; ++cb) {
          int ts = ts0 + cb * 16 + cc;
          bool ok = (ts >= start_b) && (ts <= cur + tq);
          if (!ok) s[rb][cb][r] = -1e30f;
        }
        float tm = fmaxf(s[rb][0][r], s[rb][1][r]);
#pragma unroll
        for (int m = 1; m < 16; m <<= 1) tm = fmaxf(tm, __shfl_xor(tm, m, 64));
        float mn = fmaxf(mreg[rb][r], tm);
        float a = __expf(mreg[rb][r] - mn);
        float p0 = (s[rb][0][r] < -1e29f) ? 0.0f : __expf(s[rb][0][r] - mn);
        float p1 = (s[rb][1][r] < -1e29f) ? 0.0f : __expf(s[rb][1][r] - mn);
        s[rb][0][r] = p0; s[rb][1][r] = p1;
        float rs = p0 + p1;
#pragma unroll
        for (int m = 1; m < 16; m <<= 1) rs += __shfl_xor(rs, m, 64);
        lreg[rb][r] = lreg[rb][r] * a + rs;
        mreg[rb][r] = mn;
        al[rb][r] = a;
      }
    }
    // ---- P -> LDS (C layout) -> A-frag layout
#pragma unroll
    for (int rb = 0; rb < 2; ++rb)
#pragma unroll
      for (int cb = 0; cb < 2; ++cb)
#pragma unroll
        for (int r = 0; r < 4; ++r)
          Pl[wv][rb * 16 + g * 4 + r][cb * 16 + cc] = f2bf(s[rb][cb][r]);
    __builtin_amdgcn_wave_barrier();
    bf16x8 pf[2];
#pragma unroll
    for (int rb = 0; rb < 2; ++rb)
      pf[rb] = *(const bf16x8*)&Pl[wv][rb * 16 + cc][g * 8];
    // ---- rescale + PV
#pragma unroll
    for (int rb = 0; rb < 2; ++rb)
#pragma unroll
      for (int hb = 0; hb < 8; ++hb) {
        f32x4 t = acc[rb][hb];
#pragma unroll
        for (int r = 0; r < 4; ++r) t[r] *= al[rb][r];
        acc[rb][hb] = mfma16(pf[rb], vf[hb], t);
      }
  }

  // ---- merge 4 wave-partials -> 1 block partial (scratch overlays Kl)
  float* Oscr = (float*)&Kl[0][0][0]; // 2 x 32 x 128 floats = 32 KB <= 33 KB
  auto dump = [&](int sid) {
#pragma unroll
    for (int rb = 0; rb < 2; ++rb)
#pragma unroll
      for (int hb = 0; hb < 8; ++hb)
#pragma unroll
        for (int r = 0; r < 4; ++r)
          Oscr[(sid * 32 + rb * 16 + g * 4 + r) * 128 + hb * 16 + cc] = acc[rb][hb][r];
    if (cc == 0) {
#pragma unroll
      for (int rb = 0; rb < 2; ++rb)
#pragma unroll
        for (int r = 0; r < 4; ++r) {
          mls[sid][rb * 16 + g * 4 + r][0] = mreg[rb][r];
          mls[sid][rb * 16 + g * 4 + r][1] = lreg[rb][r];
        }
    }
  };
  auto mergefrom = [&](int sid) {
    float a0s[2][4], a1s[2][4];
#pragma unroll
    for (int rb = 0; rb < 2; ++rb)
#pragma unroll
      for (int r = 0; r < 4; ++r) {
        int row = rb * 16 + g * 4 + r;
        float mp = mls[sid][row][0], lp = mls[sid][row][1];
        float M = fmaxf(mreg[rb][r], mp);
        float a0 = __expf(mreg[rb][r] - M), a1 = __expf(mp - M);
        lreg[rb][r] = lreg[rb][r] * a0 + lp * a1;
        mreg[rb][r] = M;
        a0s[rb][r] = a0; a1s[rb][r] = a1;
      }
#pragma unroll
    for (int rb = 0; rb < 2; ++rb)
#pragma unroll
      for (int hb = 0; hb < 8; ++hb)
#pragma unroll
        for (int r = 0; r < 4; ++r) {
          int row = rb * 16 + g * 4 + r;
          acc[rb][hb][r] = acc[rb][hb][r] * a0s[rb][r] +
                           Oscr[(sid * 32 + row) * 128 + hb * 16 + cc] * a1s[rb][r];
        }
  };
  __syncthreads();
  if (wv >= 2) dump(wv - 2);
  __syncthreads();
  if (wv < 2) mergefrom(wv);
  __syncthreads();
  if (wv == 1) dump(0);
  __syncthreads();
  if (wv == 0) {
    mergefrom(0);
    size_t pidx = (size_t)pair * NPART + qi;
#pragma unroll
    for (int rb = 0; rb < 2; ++rb)
#pragma unroll
      for (int hb = 0; hb < 8; ++hb)
#pragma unroll
        for (int r = 0; r < 4; ++r)
          partO[(pidx * 32 + rb * 16 + g * 4 + r) * 128 + hb * 16 + cc] = acc[rb][hb][r];
    if (cc == 0) {
#pragma unroll
      for (int rb = 0; rb < 2; ++rb)
#pragma unroll
        for (int r = 0; r < 4; ++r) {
          partML[pidx * 64 + (rb * 16 + g * 4 + r) * 2 + 0] = mreg[rb][r];
          partML[pidx * 64 + (rb * 16 + g * 4 + r) * 2 + 1] = lreg[rb][r];
        }
    }
  }
}

// ---------------------------------------------------------------------------
// Kernel D1: combine NPART partials per (b,kh). Now split 4-way: grid (64, 4).
// ---------------------------------------------------------------------------
__global__ __launch_bounds__(256) void k_combine(
    const float* __restrict__ partO, const float* __restrict__ partML,
    unsigned short* __restrict__ obf) {
  __shared__ float sc[NPART][32];
  const int pair = blockIdx.x, b = pair >> 3, kh = pair & 7;
  const int isub = blockIdx.y;
  const int tid = threadIdx.x;
  if (tid < 32) {
    float mm[NPART], ll[NPART];
    float M = -3.0e38f;
#pragma unroll
    for (int p = 0; p < NPART; ++p) {
      mm[p] = partML[((size_t)pair * NPART + p) * 64 + tid * 2 + 0];
      ll[p] = partML[((size_t)pair * NPART + p) * 64 + tid * 2 + 1];
      M = fmaxf(M, mm[p]);
    }
    float denom = 0.0f;
#pragma unroll
    for (int p = 0; p < NPART; ++p) denom += __expf(mm[p] - M) * ll[p];
    float inv = (denom > 0.0f) ? 1.0f / denom : 0.0f;
#pragma unroll
    for (int p = 0; p < NPART; ++p) sc[p][tid] = __expf(mm[p] - M) * inv;
  }
  __syncthreads();
#pragma unroll
  for (int i = 0; i < 4; ++i) {
    int idx = tid + ((isub * 4 + i) << 8);
    int row = idx >> 7, hc = idx & 127;
    float o = 0.0f;
#pragma unroll
    for (int p = 0; p < NPART; ++p)
      o += partO[(((size_t)pair * NPART + p) * 32 + row) * 128 + hc] * sc[p][row];
    int gq = row >> 4, t = row & 15, n = kh * 2 + gq;
    obf[((b * TT + t) * NN + n) * 128 + hc] = f2bf(o);
  }
}

// ---------------------------------------------------------------------------
// Kernel D2: output projection, LDS-free / barrier-free.
// out[128 x 1024] = o[128 x 2048] @ Wt2^T   (Wt2 is [d][n] bf16)
// grid (4 m, 16 d-panels of 64), block 256 = 4 waves (2m x 2n), wave 16x32.
// ---------------------------------------------------------------------------
__global__ __launch_bounds__(256) void k_out_gemm(
    const unsigned short* __restrict__ obf, const unsigned short* __restrict__ Wt2,
    float* __restrict__ out) {
  const int tid = threadIdx.x, lane = tid & 63, wv = tid >> 6;
  const int cc = lane & 15, g = lane >> 4;
  const int m0 = blockIdx.x * 32, n0 = blockIdx.y * 64;
  const int rt = wv >> 1, cb0 = (wv & 1) * 32;
  const int m = m0 + rt * 16 + cc;
  f32x4 acc[2];
#pragma unroll
  for (int i = 0; i < 2; ++i) acc[i] = (f32x4)0.0f;

#pragma unroll 4
  for (int k0 = 0; k0 < 2048; k0 += 32) {
    bf16x8 af = *(const bf16x8*)(obf + (size_t)m * 2048 + k0 + g * 8);
#pragma unroll
    for (int ct = 0; ct < 2; ++ct) {
      const int d = n0 + cb0 + ct * 16 + cc;
      bf16x8 bf = *(const bf16x8*)(Wt2 + (size_t)d * 2048 + k0 + g * 8);
      acc[ct] = mfma16(af, bf, acc[ct]);
    }
  }
#pragma unroll
  for (int ct = 0; ct < 2; ++ct)
#pragma unroll
    for (int r = 0; r < 4; ++r)
      out[(size_t)(m0 + rt * 16 + g * 4 + r) * 1024 + n0 + cb0 + ct * 16 + cc] = acc[ct][r];
}

// ---------------------------------------------------------------------------
extern "C" void kernel_launch(void* const* d_in, const int* in_sizes, int n_in,
                              void* d_out, int out_size, void* d_ws, size_t ws_size,
                              hipStream_t stream) {
  (void)in_sizes; (void)n_in; (void)out_size; (void)ws_size;
  const float* x   = (const float*)d_in[0];
  const float* Wq  = (const float*)d_in[1];
  const float* Wk  = (const float*)d_in[2];
  const float* Wv  = (const float*)d_in[3];
  const float* Wo  = (const float*)d_in[4];
  const float* qs  = (const float*)d_in[5];
  const float* ks  = (const float*)d_in[6];
  const float* kc  = (const float*)d_in[7];
  const float* vc  = (const float*)d_in[8];
  const int* seg   = (const int*)d_in[9];
  const int* sind  = (const int*)d_in[10];
  const int* curp  = (const int*)d_in[11];
  float* out = (float*)d_out;

  char* ws = (char*)d_ws;
  float*          qkv    = (float*)(ws + 0);                 // 2,097,152 B
  unsigned short* qa     = (unsigned short*)(ws + 2097152);  //   524,288 B
  unsigned short* ka     = (unsigned short*)(ws + 2621440);  //   262,144 B
  unsigned short* va     = (unsigned short*)(ws + 2883584);  //   262,144 B
  float*          partO  = (float*)(ws + 3145728);           // 8,388,608 B
  float*          partML = (float*)(ws + 11534336);          //   131,072 B
  unsigned short* obf    = (unsigned short*)(ws + 11665408); //   524,288 B
  unsigned short* Wt1    = (unsigned short*)(ws + 12189696); // 8,388,608 B
  unsigned short* Wt2    = (unsigned short*)(ws + 20578304); // 4,194,304 B

  k_wtrans<<<dim3(32, 32, 4), 256, 0, stream>>>(Wq, Wk, Wv, Wo, Wt1, Wt2);
  k_qkv_gemm<<<dim3(4, 32), 256, 0, stream>>>(x, Wt1, qkv);
  k_normrope<<<dim3(128, 32), 128, 0, stream>>>(qkv, qs, ks, seg, curp, qa, ka, va);
  k_attn<<<dim3(64, NPART), 256, 0, stream>>>(kc, vc, qa, ka, va, seg, sind, curp, partO, partML);
  k_combine<<<dim3(64, 4), 256, 0, stream>>>(partO, partML, obf);
  k_out_gemm<<<dim3(4, 16), 256, 0, stream>>>(obf, Wt2, out);
}